// Round 6
// baseline (477.269 us; speedup 1.0000x reference)
//
#include <hip/hip_runtime.h>
#include <cstdint>

// ---------------------------------------------------------------------------
// FM4Bio transformer layer on MI355X (gfx950).
// LN1 -> fused QKV GEMM (+RoPE, +scale into Q) -> flash attn (128 KV tile,
//   two-pass PV, 48KB LDS -> 3 blocks/CU) -> Wo GEMM (+resid) -> LN2
//   -> W1 GEMM (+fused swiglu) -> W2 GEMM (+resid)
// GEMMs: 16x16x32 bf16 MFMA, BK=64, XOR-(row&7) chunk swizzle (measured 0
// conflicts). Flash: XOR swizzles, exp2-based softmax, deferred l-reduction.
// ---------------------------------------------------------------------------

typedef __bf16 bf16;
typedef __bf16 bf16x8 __attribute__((ext_vector_type(8)));
typedef float f32x4 __attribute__((ext_vector_type(4)));

#define B_ 2
#define S_ 2048
#define DM_ 1024
#define H_ 16
#define HD_ 64
#define INTER_ 4096

#define MFMA16(a, b, c) __builtin_amdgcn_mfma_f32_16x16x32_bf16(a, b, c, 0, 0, 0)

#if __has_builtin(__builtin_amdgcn_exp2f)
#define EXP2F(x) __builtin_amdgcn_exp2f(x)
#else
#define EXP2F(x) __expf((x) * 0.6931471805599453f)
#endif

__device__ __forceinline__ void cp16(void* lds, const void* g) {
  __builtin_amdgcn_global_load_lds(
      (const __attribute__((address_space(1))) void*)(uintptr_t)g,
      (__attribute__((address_space(3))) void*)(uint32_t)(uintptr_t)lds,
      16, 0, 0);
}

// ---------------------------------------------------------------------------
// Batched weight transpose: 4x fp32 [1024][1024] -> bf16 [1024][1024]^T
// ---------------------------------------------------------------------------
__global__ void transpose4_f32_bf16(const float* __restrict__ w0,
                                    const float* __restrict__ w1,
                                    const float* __restrict__ w2,
                                    const float* __restrict__ w3,
                                    bf16* __restrict__ o0, bf16* __restrict__ o1,
                                    bf16* __restrict__ o2, bf16* __restrict__ o3) {
  __shared__ float tile[32][33];
  const float* in = (blockIdx.z == 0) ? w0 : (blockIdx.z == 1) ? w1
                    : (blockIdx.z == 2) ? w2 : w3;
  bf16* out = (blockIdx.z == 0) ? o0 : (blockIdx.z == 1) ? o1
              : (blockIdx.z == 2) ? o2 : o3;
  int n0 = blockIdx.x * 32, k0 = blockIdx.y * 32;
  int tx = threadIdx.x, ty = threadIdx.y;  // 32 x 8
#pragma unroll
  for (int i = 0; i < 32; i += 8)
    tile[ty + i][tx] = in[(size_t)(k0 + ty + i) * 1024 + n0 + tx];
  __syncthreads();
#pragma unroll
  for (int i = 0; i < 32; i += 8)
    out[(size_t)(n0 + ty + i) * 1024 + k0 + tx] = (bf16)tile[tx][ty + i];
}

// generic fp32 [K][N] -> bf16 [N][K]
__global__ void transpose_f32_bf16(const float* __restrict__ in,
                                   bf16* __restrict__ out, int K, int N) {
  __shared__ float tile[32][33];
  int n0 = blockIdx.x * 32, k0 = blockIdx.y * 32;
  int tx = threadIdx.x, ty = threadIdx.y;
#pragma unroll
  for (int i = 0; i < 32; i += 8)
    tile[ty + i][tx] = in[(size_t)(k0 + ty + i) * N + n0 + tx];
  __syncthreads();
#pragma unroll
  for (int i = 0; i < 32; i += 8)
    out[(size_t)(n0 + ty + i) * K + k0 + tx] = (bf16)tile[tx][ty + i];
}

// W1 transpose with swiglu-interleave remap: orig col n (0..8191) ->
// row r = ((n&4095)>>3)*16 + ((n>>12)<<3) + (n&7).
__global__ void transpose_w1(const float* __restrict__ in,
                             bf16* __restrict__ out) {
  __shared__ float tile[32][33];
  int n0 = blockIdx.x * 32, k0 = blockIdx.y * 32;
  int tx = threadIdx.x, ty = threadIdx.y;
#pragma unroll
  for (int i = 0; i < 32; i += 8)
    tile[ty + i][tx] = in[(size_t)(k0 + ty + i) * (2 * INTER_) + n0 + tx];
  __syncthreads();
#pragma unroll
  for (int i = 0; i < 32; i += 8) {
    int n = n0 + ty + i;
    int r = ((n & 4095) >> 3) * 16 + ((n >> 12) << 3) + (n & 7);
    out[(size_t)r * DM_ + k0 + tx] = (bf16)tile[tx][ty + i];
  }
}

// bf16 [K][N] -> bf16 [N][K], batched over blockIdx.z (V -> V^T per head)
__global__ void transpose_bf16(const bf16* __restrict__ in,
                               bf16* __restrict__ out, int K, int N) {
  __shared__ bf16 tile[32][33];
  const size_t mo = (size_t)blockIdx.z * K * N;
  int n0 = blockIdx.x * 32, k0 = blockIdx.y * 32;
  int tx = threadIdx.x, ty = threadIdx.y;
#pragma unroll
  for (int i = 0; i < 32; i += 8)
    tile[ty + i][tx] = in[mo + (size_t)(k0 + ty + i) * N + n0 + tx];
  __syncthreads();
#pragma unroll
  for (int i = 0; i < 32; i += 8)
    out[mo + (size_t)(n0 + ty + i) * K + k0 + tx] = tile[tx][ty + i];
}

// ---------------------------------------------------------------------------
// LayerNorm: fp32 [rows][1024] -> bf16 [rows][1024]
// ---------------------------------------------------------------------------
__global__ __launch_bounds__(256) void ln_bf16(const float* __restrict__ x,
                                               const float* __restrict__ g,
                                               const float* __restrict__ bta,
                                               bf16* __restrict__ out) {
  int row = blockIdx.x;
  int tid = threadIdx.x;
  const float4* xr = (const float4*)(x + (size_t)row * DM_);
  float4 v = xr[tid];
  float s1 = v.x + v.y + v.z + v.w;
  float s2 = v.x * v.x + v.y * v.y + v.z * v.z + v.w * v.w;
#pragma unroll
  for (int off = 32; off; off >>= 1) {
    s1 += __shfl_xor(s1, off);
    s2 += __shfl_xor(s2, off);
  }
  __shared__ float rA[4], rB[4];
  int wave = tid >> 6, lane = tid & 63;
  if (!lane) { rA[wave] = s1; rB[wave] = s2; }
  __syncthreads();
  float t1 = rA[0] + rA[1] + rA[2] + rA[3];
  float t2 = rB[0] + rB[1] + rB[2] + rB[3];
  float mean = t1 * (1.0f / DM_);
  float var = t2 * (1.0f / DM_) - mean * mean;
  float rstd = rsqrtf(var + 1e-5f);
  int col = tid * 4;
  float4 gv = ((const float4*)g)[tid];
  float4 bv = ((const float4*)bta)[tid];
  bf16* o = out + (size_t)row * DM_ + col;
  o[0] = (bf16)((v.x - mean) * rstd * gv.x + bv.x);
  o[1] = (bf16)((v.y - mean) * rstd * gv.y + bv.y);
  o[2] = (bf16)((v.z - mean) * rstd * gv.z + bv.z);
  o[3] = (bf16)((v.w - mean) * rstd * gv.w + bv.w);
}

// ---------------------------------------------------------------------------
// GEMM: C[M,N] = A[M,K](bf16) * Bt[N,K]^T(bf16), 16x16x32 MFMA, BK=64.
// LDS rows are 64 bf16 = 128 B; chunk slot = global_chunk ^ (row&7).
// EPI 0: fused QKV (block-uniform q/k/v select, RoPE, scale into Q)
// EPI 2: +bias +resid(fp32 [M,N]) -> fp32 [M,N]
// EPI 4: W1 + fused swiglu (interleaved W1t layout) -> bf16 [M,INTER]
// ---------------------------------------------------------------------------
template <int EPI, int BN>
__global__ __launch_bounds__(256, 2) void gemm_bt(
    const bf16* __restrict__ A, const bf16* __restrict__ Bt,
    const float* __restrict__ b0, const float* __restrict__ b1p,
    const float* __restrict__ b2p, const float* __restrict__ rope,
    const float* __restrict__ resid, void* __restrict__ outp, int N, int K) {
  constexpr int TM = (BN == 128) ? 4 : 2;
  __shared__ __align__(16) bf16 As[128 * 64];
  __shared__ __align__(16) bf16 Bs[BN * 64];
  const int tid = threadIdx.x;
  const int lane = tid & 63, wave = tid >> 6;
  const int c = lane & 15, quad = lane >> 4;
  const int wr = (BN == 128) ? (wave >> 1) : wave;
  const int wc = (BN == 128) ? (wave & 1) : 0;
  const int mbase = wr * (16 * TM), nbase = wc * 64;
  const int bm0 = blockIdx.y * 128, bn0 = blockIdx.x * BN;

  f32x4 acc[TM][4];
  const f32x4 z4 = {0.f, 0.f, 0.f, 0.f};
#pragma unroll
  for (int i = 0; i < TM; ++i)
#pragma unroll
    for (int j = 0; j < 4; ++j) acc[i][j] = z4;

  for (int k0 = 0; k0 < K; k0 += 64) {
    __syncthreads();
#pragma unroll
    for (int it = 0; it < 4; ++it) {  // A: 1024 chunks of 16B (128 rows x 8)
      int idx = tid + it * 256;
      int row = idx >> 3, g = (idx ^ row) & 7;
      cp16(As + (size_t)idx * 8, A + (size_t)(bm0 + row) * K + k0 + g * 8);
    }
#pragma unroll
    for (int it = 0; it < BN / 32; ++it) {  // B: BN*8 chunks
      int idx = tid + it * 256;
      int row = idx >> 3, g = (idx ^ row) & 7;
      cp16(Bs + (size_t)idx * 8, Bt + (size_t)(bn0 + row) * K + k0 + g * 8);
    }
    __syncthreads();
#pragma unroll
    for (int s = 0; s < 2; ++s) {  // two k-steps of 32
      bf16x8 af[TM], bfr[4];
#pragma unroll
      for (int ti = 0; ti < TM; ++ti) {
        int row = mbase + ti * 16 + c;
        af[ti] = *(const bf16x8*)(As + row * 64 + ((s * 4 + quad) ^ (row & 7)) * 8);
      }
#pragma unroll
      for (int tj = 0; tj < 4; ++tj) {
        int row = nbase + tj * 16 + c;
        bfr[tj] = *(const bf16x8*)(Bs + row * 64 + ((s * 4 + quad) ^ (row & 7)) * 8);
      }
#pragma unroll
      for (int ti = 0; ti < TM; ++ti)
#pragma unroll
        for (int tj = 0; tj < 4; ++tj)
          acc[ti][tj] = MFMA16(af[ti], bfr[tj], acc[ti][tj]);
    }
  }

  if constexpr (EPI == 2) {
    float* o = (float*)outp;
#pragma unroll
    for (int ti = 0; ti < TM; ++ti)
#pragma unroll
      for (int r = 0; r < 4; ++r) {
        int gm = bm0 + mbase + ti * 16 + quad * 4 + r;
        const float* rrow = resid + (size_t)gm * N;
        float* orow = o + (size_t)gm * N;
#pragma unroll
        for (int tj = 0; tj < 4; ++tj) {
          int gn = bn0 + nbase + tj * 16 + c;
          orow[gn] = acc[ti][tj][r] + b0[gn] + rrow[gn];
        }
      }
  } else if constexpr (EPI == 4) {
    bf16* act = (bf16*)outp;
#pragma unroll
    for (int ti = 0; ti < TM; ++ti)
#pragma unroll
      for (int r = 0; r < 4; ++r) {
        int gm = bm0 + mbase + ti * 16 + quad * 4 + r;
        bf16* arow = act + (size_t)gm * INTER_;
#pragma unroll
        for (int tj = 0; tj < 4; ++tj) {
          int gn = bn0 + nbase + tj * 16 + c;
          int g = gn >> 4, t = gn & 7, hi = (gn >> 3) & 1;
          float val = acc[ti][tj][r] + b0[g * 8 + t + (hi << 12)];
          float part = __shfl_xor(val, 8);  // partner col ^8 (h1 for h0 lanes)
          if (!hi) {
            float sg = part / (1.0f + __expf(-part));
            arow[g * 8 + t] = (bf16)(val * sg);
          }
        }
      }
  } else {  // EPI 0: fused QKV; mtx select is block-uniform (128 | 1024 tiles)
    bf16* o = (bf16*)outp;
    const int mtx = bn0 >> 10;  // 0=q 1=k 2=v
    const float* bp = (mtx == 0) ? b0 : (mtx == 1) ? b1p : b2p;
#pragma unroll
    for (int ti = 0; ti < TM; ++ti)
#pragma unroll
      for (int r = 0; r < 4; ++r) {
        int gm = bm0 + mbase + ti * 16 + quad * 4 + r;
        int s = gm & (S_ - 1);
        int bb = gm >> 11;
#pragma unroll
        for (int tj = 0; tj < 4; ++tj) {
          int gn = bn0 + nbase + tj * 16 + c;
          int ci = gn & 1023, hd = gn & 63;
          float val = acc[ti][tj][r] + bp[ci];
          if (mtx < 2) {
            int pj = (tj & 2) ? tj - 2 : tj + 2;
            int ci2 = (tj & 2) ? ci - 32 : ci + 32;
            float part = acc[ti][pj][r] + bp[ci2];
            if (!(tj & 2)) part = -part;
            float fr = rope[s * HD_ + hd];
            float sn, cs;
            __sincosf(fr, &sn, &cs);
            val = val * cs + part * sn;
            if (mtx == 0) val *= 0.1803368867f;  // (1/8) * log2(e)
          }
          o[(size_t)mtx * (32 * S_ * HD_) +
            (((size_t)(bb * H_ + ((gn >> 6) & 15))) * S_ + s) * HD_ + hd] =
              (bf16)val;
        }
      }
  }
}

// ---------------------------------------------------------------------------
// Flash attention: q(pre-scaled by log2e/8),k bf16 [B*H][S][HD],
// vt bf16 [B*H][HD][S], mask fp32 [B][S], ctx bf16 [B][S][Dm].
// Block = 128 q rows x head, 512 threads (8 waves x 16 q rows), KV tile 128
// processed as two 64-KV halves (QK -> exp -> P-store -> PV per half).
// LDS = Ks 16K + Vs 16K + Ps 16K = 48KB -> 3 blocks/CU.
// ---------------------------------------------------------------------------
__global__ __launch_bounds__(512, 6) void flash_attn(
    const bf16* __restrict__ q, const bf16* __restrict__ k,
    const bf16* __restrict__ vt, const float* __restrict__ mask,
    bf16* __restrict__ ctx) {
  __shared__ __align__(16) bf16 Ks[128 * 64];   // [kv][hd], swizzled
  __shared__ __align__(16) bf16 Vs[64 * 128];   // [hd][s],  swizzled
  __shared__ __align__(16) bf16 Ps[8][16 * 64]; // per-wave P half-tile

  const int tid = threadIdx.x;
  const int lane = tid & 63, wave = tid >> 6;
  const int c = lane & 15, quad = lane >> 4;
  const int bh = blockIdx.y, b = bh >> 4, h = bh & 15;
  const int q0 = blockIdx.x * 128;

  const bf16* qh = q + (size_t)bh * S_ * HD_;
  const bf16* kh = k + (size_t)bh * S_ * HD_;
  const bf16* vh = vt + (size_t)bh * HD_ * S_;
  const float* mrow = mask + (size_t)b * S_;

  int qrow = q0 + wave * 16 + c;
  bf16x8 qa0 = *(const bf16x8*)(qh + (size_t)qrow * HD_ + quad * 8);
  bf16x8 qa1 = *(const bf16x8*)(qh + (size_t)qrow * HD_ + 32 + quad * 8);

  const f32x4 z4 = {0.f, 0.f, 0.f, 0.f};
  f32x4 o[4] = {z4, z4, z4, z4};
  float l_i[4] = {0.f, 0.f, 0.f, 0.f};
  bf16* pw = Ps[wave];

  for (int k0 = 0; k0 < S_; k0 += 128) {
    __syncthreads();
#pragma unroll
    for (int it = 0; it < 2; ++it) {  // Ks: 1024 chunks (row=128B=8 chunks)
      int idx = tid + it * 512;
      int row = idx >> 3, chg = (idx & 7) ^ (row & 7);
      cp16(Ks + (size_t)idx * 8, kh + (size_t)(k0 + row) * HD_ + chg * 8);
    }
#pragma unroll
    for (int it = 0; it < 2; ++it) {  // Vs: 1024 chunks (row=256B=16 chunks)
      int idx = tid + it * 512;
      int row = idx >> 4, chg = (idx & 15) ^ (row & 15);
      cp16(Vs + (size_t)idx * 8, vh + (size_t)row * S_ + k0 + chg * 8);
    }
    __syncthreads();

#pragma unroll
    for (int hh = 0; hh < 2; ++hh) {  // two 64-KV halves
      // S = Q K^T : 16 q rows x 64 kv cols per wave
      f32x4 sv[4];
      float mv2[4];
#pragma unroll
      for (int tj = 0; tj < 4; ++tj) {
        int krow = hh * 64 + tj * 16 + c;
        const bf16* kr = Ks + krow * 64;
        bf16x8 kb0 = *(const bf16x8*)(kr + (quad ^ (krow & 7)) * 8);
        bf16x8 kb1 = *(const bf16x8*)(kr + ((4 + quad) ^ (krow & 7)) * 8);
        sv[tj] = MFMA16(qa0, kb0, z4);
        sv[tj] = MFMA16(qa1, kb1, sv[tj]);
        mv2[tj] = mrow[k0 + krow] * 1.4426950408889634f;
      }

      // p = 2^(s + m*log2e); masked entries contribute to l but p := 0
#pragma unroll
      for (int tj = 0; tj < 4; ++tj) {
        bool msk = mv2[tj] < -1.4426950e-5f;
#pragma unroll
        for (int r = 0; r < 4; ++r) {
          float e = EXP2F(sv[tj][r] + mv2[tj]);
          l_i[r] += e;
          float p = msk ? 0.f : e;
          int prow = quad * 4 + r;
          int pos = (tj * 2 + (c >> 3)) ^ (prow & 7);
          pw[prow * 64 + pos * 8 + (c & 7)] = (bf16)p;
        }
      }
      asm volatile("s_waitcnt lgkmcnt(0)" ::: "memory");
      bf16x8 pa0 = *(const bf16x8*)(pw + c * 64 + (quad ^ (c & 7)) * 8);
      bf16x8 pa1 = *(const bf16x8*)(pw + c * 64 + ((quad + 4) ^ (c & 7)) * 8);

      // O += P V  (kv range hh*64 .. hh*64+63)
#pragma unroll
      for (int tn = 0; tn < 4; ++tn) {
        int vrow = tn * 16 + c;
        const bf16* vr = Vs + vrow * 128;
        bf16x8 vb0 =
            *(const bf16x8*)(vr + (((hh * 2 + 0) * 4 + quad) ^ (vrow & 15)) * 8);
        bf16x8 vb1 =
            *(const bf16x8*)(vr + (((hh * 2 + 1) * 4 + quad) ^ (vrow & 15)) * 8);
        o[tn] = MFMA16(pa0, vb0, o[tn]);
        o[tn] = MFMA16(pa1, vb1, o[tn]);
      }
    }
  }

  // deferred 16-lane l reduction + epilogue
#pragma unroll
  for (int r = 0; r < 4; ++r) {
    float l = l_i[r];
#pragma unroll
    for (int off = 1; off < 16; off <<= 1) l += __shfl_xor(l, off);
    float inv = 1.0f / l;
    int qout = q0 + wave * 16 + quad * 4 + r;
    bf16* crow = ctx + ((size_t)(b * S_ + qout)) * DM_ + h * HD_;
#pragma unroll
    for (int tn = 0; tn < 4; ++tn) crow[tn * 16 + c] = (bf16)(o[tn][r] * inv);
  }
}

// ---------------------------------------------------------------------------
// Launch
// ---------------------------------------------------------------------------
extern "C" void kernel_launch(void* const* d_in, const int* in_sizes, int n_in,
                              void* d_out, int out_size, void* d_ws,
                              size_t ws_size, hipStream_t stream) {
  const float* hs   = (const float*)d_in[0];
  const float* mask = (const float*)d_in[1];
  const float* rope = (const float*)d_in[2];
  const float* Wq = (const float*)d_in[3];  const float* bq = (const float*)d_in[4];
  const float* Wk = (const float*)d_in[5];  const float* bk = (const float*)d_in[6];
  const float* Wv = (const float*)d_in[7];  const float* bv = (const float*)d_in[8];
  const float* Wo = (const float*)d_in[9];  const float* bo = (const float*)d_in[10];
  const float* g1 = (const float*)d_in[11]; const float* be1 = (const float*)d_in[12];
  const float* g2 = (const float*)d_in[13]; const float* be2 = (const float*)d_in[14];
  const float* W1 = (const float*)d_in[15]; const float* b1 = (const float*)d_in[16];
  const float* W2 = (const float*)d_in[17]; const float* b2 = (const float*)d_in[18];
  float* out = (float*)d_out;
  char* ws = (char*)d_ws;
  const size_t MB = 1ull << 20;

  // workspace layout (peak 128 MiB)
  bf16* Wqkvt = (bf16*)(ws + 0 * MB);    // [3072][1024]  (6 MB)
  bf16* Wot = (bf16*)(ws + 6 * MB);      // [1024][1024]  (2 MB)
  bf16* W1t = (bf16*)(ws + 8 * MB);      // [8192][1024] interleaved (16 MB)
  bf16* W2t = (bf16*)(ws + 24 * MB);     // [1024][4096]  (8 MB)
  bf16* xln = (bf16*)(ws + 32 * MB);     // [4096][1024]  (8 MB)
  float* hid = (float*)(ws + 40 * MB);   // [4096][1024] fp32 (16 MB)
  bf16* qkv = (bf16*)(ws + 56 * MB);     // 3 x [32][2048][64]  (24 MB)
  bf16* vtr = (bf16*)(ws + 80 * MB);     // [32][64][2048]  (8 MB)
  bf16* ctx = (bf16*)(ws + 88 * MB);     // [4096][1024]  (8 MB)
  bf16* act = (bf16*)(ws + 96 * MB);     // [4096][4096]  (32 MB)

  dim3 blk(256);
  dim3 tb(32, 8);

  // weight conversion + transpose
  transpose4_f32_bf16<<<dim3(32, 32, 4), tb, 0, stream>>>(
      Wq, Wk, Wv, Wo, Wqkvt, Wqkvt + (1 << 20), Wqkvt + (2 << 20), Wot);
  transpose_w1<<<dim3(256, 32), tb, 0, stream>>>(W1, W1t);
  transpose_f32_bf16<<<dim3(32, 128), tb, 0, stream>>>(W2, W2t, 4096, 1024);

  // LN1
  ln_bf16<<<4096, blk, 0, stream>>>(hs, g1, be1, xln);

  // fused QKV projection (RoPE q/k, scale into q, heads layout)
  gemm_bt<0, 128><<<dim3(24, 32), blk, 0, stream>>>(
      xln, Wqkvt, bq, bk, bv, rope, nullptr, qkv, 3072, 1024);

  // V -> V^T per head
  transpose_bf16<<<dim3(2, 64, 32), tb, 0, stream>>>(
      qkv + (size_t)2 * 32 * S_ * HD_, vtr, 2048, 64);

  // flash attention (128 q rows per block, 512 threads, 3 blocks/CU)
  flash_attn<<<dim3(16, 32), dim3(512), 0, stream>>>(
      qkv, qkv + (size_t)32 * S_ * HD_, vtr, mask, ctx);

  // Wo projection + residual -> hidden (fp32)
  gemm_bt<2, 64><<<dim3(16, 32), blk, 0, stream>>>(
      ctx, Wot, bo, nullptr, nullptr, nullptr, hs, hid, 1024, 1024);

  // LN2
  ln_bf16<<<4096, blk, 0, stream>>>(hid, g2, be2, xln);

  // W1 GEMM + fused swiglu -> act
  gemm_bt<4, 128><<<dim3(64, 32), blk, 0, stream>>>(
      xln, W1t, b1, nullptr, nullptr, nullptr, nullptr, act, 8192, 1024);

  // W2 GEMM + residual -> out (fp32)
  gemm_bt<2, 64><<<dim3(16, 32), blk, 0, stream>>>(
      act, W2t, b2, nullptr, nullptr, nullptr, hid, out, 1024, 4096);

  (void)in_sizes; (void)n_in; (void)out_size; (void)ws_size;
}

// Round 7
// 452.234 us; speedup vs baseline: 1.0554x; 1.0554x over previous
//
#include <hip/hip_runtime.h>
#include <cstdint>

// ---------------------------------------------------------------------------
// FM4Bio transformer layer on MI355X (gfx950).
// LN1 -> fused QKV GEMM (+RoPE, +scale into Q) -> flash attn (64 q-rows/block,
//   128 KV tile, two-pass PV, 40KB LDS -> 4 blocks/CU) -> Wo GEMM (+resid)
//   -> LN2 -> W1 GEMM (+fused swiglu) -> W2 GEMM (+resid)
// GEMMs: 16x16x32 bf16 MFMA, BK=64, XOR-(row&7) chunk swizzle (measured 0
// conflicts). Flash: XOR swizzles, exp2-based softmax, deferred l-reduction.
// NOTE: launch_bounds must stay loose enough to avoid VGPR spills (R6 lesson:
// (512,6) forced spilling -> 141 MB scratch writes, +20 us).
// ---------------------------------------------------------------------------

typedef __bf16 bf16;
typedef __bf16 bf16x8 __attribute__((ext_vector_type(8)));
typedef float f32x4 __attribute__((ext_vector_type(4)));

#define B_ 2
#define S_ 2048
#define DM_ 1024
#define H_ 16
#define HD_ 64
#define INTER_ 4096

#define MFMA16(a, b, c) __builtin_amdgcn_mfma_f32_16x16x32_bf16(a, b, c, 0, 0, 0)

#if __has_builtin(__builtin_amdgcn_exp2f)
#define EXP2F(x) __builtin_amdgcn_exp2f(x)
#else
#define EXP2F(x) __expf((x) * 0.6931471805599453f)
#endif

__device__ __forceinline__ void cp16(void* lds, const void* g) {
  __builtin_amdgcn_global_load_lds(
      (const __attribute__((address_space(1))) void*)(uintptr_t)g,
      (__attribute__((address_space(3))) void*)(uint32_t)(uintptr_t)lds,
      16, 0, 0);
}

// ---------------------------------------------------------------------------
// Batched weight transpose: 4x fp32 [1024][1024] -> bf16 [1024][1024]^T
// ---------------------------------------------------------------------------
__global__ void transpose4_f32_bf16(const float* __restrict__ w0,
                                    const float* __restrict__ w1,
                                    const float* __restrict__ w2,
                                    const float* __restrict__ w3,
                                    bf16* __restrict__ o0, bf16* __restrict__ o1,
                                    bf16* __restrict__ o2, bf16* __restrict__ o3) {
  __shared__ float tile[32][33];
  const float* in = (blockIdx.z == 0) ? w0 : (blockIdx.z == 1) ? w1
                    : (blockIdx.z == 2) ? w2 : w3;
  bf16* out = (blockIdx.z == 0) ? o0 : (blockIdx.z == 1) ? o1
              : (blockIdx.z == 2) ? o2 : o3;
  int n0 = blockIdx.x * 32, k0 = blockIdx.y * 32;
  int tx = threadIdx.x, ty = threadIdx.y;  // 32 x 8
#pragma unroll
  for (int i = 0; i < 32; i += 8)
    tile[ty + i][tx] = in[(size_t)(k0 + ty + i) * 1024 + n0 + tx];
  __syncthreads();
#pragma unroll
  for (int i = 0; i < 32; i += 8)
    out[(size_t)(n0 + ty + i) * 1024 + k0 + tx] = (bf16)tile[tx][ty + i];
}

// generic fp32 [K][N] -> bf16 [N][K]
__global__ void transpose_f32_bf16(const float* __restrict__ in,
                                   bf16* __restrict__ out, int K, int N) {
  __shared__ float tile[32][33];
  int n0 = blockIdx.x * 32, k0 = blockIdx.y * 32;
  int tx = threadIdx.x, ty = threadIdx.y;
#pragma unroll
  for (int i = 0; i < 32; i += 8)
    tile[ty + i][tx] = in[(size_t)(k0 + ty + i) * N + n0 + tx];
  __syncthreads();
#pragma unroll
  for (int i = 0; i < 32; i += 8)
    out[(size_t)(n0 + ty + i) * K + k0 + tx] = (bf16)tile[tx][ty + i];
}

// W1 transpose with swiglu-interleave remap: orig col n (0..8191) ->
// row r = ((n&4095)>>3)*16 + ((n>>12)<<3) + (n&7).
__global__ void transpose_w1(const float* __restrict__ in,
                             bf16* __restrict__ out) {
  __shared__ float tile[32][33];
  int n0 = blockIdx.x * 32, k0 = blockIdx.y * 32;
  int tx = threadIdx.x, ty = threadIdx.y;
#pragma unroll
  for (int i = 0; i < 32; i += 8)
    tile[ty + i][tx] = in[(size_t)(k0 + ty + i) * (2 * INTER_) + n0 + tx];
  __syncthreads();
#pragma unroll
  for (int i = 0; i < 32; i += 8) {
    int n = n0 + ty + i;
    int r = ((n & 4095) >> 3) * 16 + ((n >> 12) << 3) + (n & 7);
    out[(size_t)r * DM_ + k0 + tx] = (bf16)tile[tx][ty + i];
  }
}

// bf16 [K][N] -> bf16 [N][K], batched over blockIdx.z (V -> V^T per head)
__global__ void transpose_bf16(const bf16* __restrict__ in,
                               bf16* __restrict__ out, int K, int N) {
  __shared__ bf16 tile[32][33];
  const size_t mo = (size_t)blockIdx.z * K * N;
  int n0 = blockIdx.x * 32, k0 = blockIdx.y * 32;
  int tx = threadIdx.x, ty = threadIdx.y;
#pragma unroll
  for (int i = 0; i < 32; i += 8)
    tile[ty + i][tx] = in[mo + (size_t)(k0 + ty + i) * N + n0 + tx];
  __syncthreads();
#pragma unroll
  for (int i = 0; i < 32; i += 8)
    out[mo + (size_t)(n0 + ty + i) * K + k0 + tx] = tile[tx][ty + i];
}

// ---------------------------------------------------------------------------
// LayerNorm: fp32 [rows][1024] -> bf16 [rows][1024]
// ---------------------------------------------------------------------------
__global__ __launch_bounds__(256) void ln_bf16(const float* __restrict__ x,
                                               const float* __restrict__ g,
                                               const float* __restrict__ bta,
                                               bf16* __restrict__ out) {
  int row = blockIdx.x;
  int tid = threadIdx.x;
  const float4* xr = (const float4*)(x + (size_t)row * DM_);
  float4 v = xr[tid];
  float s1 = v.x + v.y + v.z + v.w;
  float s2 = v.x * v.x + v.y * v.y + v.z * v.z + v.w * v.w;
#pragma unroll
  for (int off = 32; off; off >>= 1) {
    s1 += __shfl_xor(s1, off);
    s2 += __shfl_xor(s2, off);
  }
  __shared__ float rA[4], rB[4];
  int wave = tid >> 6, lane = tid & 63;
  if (!lane) { rA[wave] = s1; rB[wave] = s2; }
  __syncthreads();
  float t1 = rA[0] + rA[1] + rA[2] + rA[3];
  float t2 = rB[0] + rB[1] + rB[2] + rB[3];
  float mean = t1 * (1.0f / DM_);
  float var = t2 * (1.0f / DM_) - mean * mean;
  float rstd = rsqrtf(var + 1e-5f);
  int col = tid * 4;
  float4 gv = ((const float4*)g)[tid];
  float4 bv = ((const float4*)bta)[tid];
  bf16* o = out + (size_t)row * DM_ + col;
  o[0] = (bf16)((v.x - mean) * rstd * gv.x + bv.x);
  o[1] = (bf16)((v.y - mean) * rstd * gv.y + bv.y);
  o[2] = (bf16)((v.z - mean) * rstd * gv.z + bv.z);
  o[3] = (bf16)((v.w - mean) * rstd * gv.w + bv.w);
}

// ---------------------------------------------------------------------------
// GEMM: C[M,N] = A[M,K](bf16) * Bt[N,K]^T(bf16), 16x16x32 MFMA, BK=64.
// LDS rows are 64 bf16 = 128 B; chunk slot = global_chunk ^ (row&7).
// EPI 0: fused QKV (block-uniform q/k/v select, RoPE, scale into Q)
// EPI 2: +bias +resid(fp32 [M,N]) -> fp32 [M,N]
// EPI 4: W1 + fused swiglu (interleaved W1t layout) -> bf16 [M,INTER]
// ---------------------------------------------------------------------------
template <int EPI, int BN>
__global__ __launch_bounds__(256, 2) void gemm_bt(
    const bf16* __restrict__ A, const bf16* __restrict__ Bt,
    const float* __restrict__ b0, const float* __restrict__ b1p,
    const float* __restrict__ b2p, const float* __restrict__ rope,
    const float* __restrict__ resid, void* __restrict__ outp, int N, int K) {
  constexpr int TM = (BN == 128) ? 4 : 2;
  __shared__ __align__(16) bf16 As[128 * 64];
  __shared__ __align__(16) bf16 Bs[BN * 64];
  const int tid = threadIdx.x;
  const int lane = tid & 63, wave = tid >> 6;
  const int c = lane & 15, quad = lane >> 4;
  const int wr = (BN == 128) ? (wave >> 1) : wave;
  const int wc = (BN == 128) ? (wave & 1) : 0;
  const int mbase = wr * (16 * TM), nbase = wc * 64;
  const int bm0 = blockIdx.y * 128, bn0 = blockIdx.x * BN;

  f32x4 acc[TM][4];
  const f32x4 z4 = {0.f, 0.f, 0.f, 0.f};
#pragma unroll
  for (int i = 0; i < TM; ++i)
#pragma unroll
    for (int j = 0; j < 4; ++j) acc[i][j] = z4;

  for (int k0 = 0; k0 < K; k0 += 64) {
    __syncthreads();
#pragma unroll
    for (int it = 0; it < 4; ++it) {  // A: 1024 chunks of 16B (128 rows x 8)
      int idx = tid + it * 256;
      int row = idx >> 3, g = (idx ^ row) & 7;
      cp16(As + (size_t)idx * 8, A + (size_t)(bm0 + row) * K + k0 + g * 8);
    }
#pragma unroll
    for (int it = 0; it < BN / 32; ++it) {  // B: BN*8 chunks
      int idx = tid + it * 256;
      int row = idx >> 3, g = (idx ^ row) & 7;
      cp16(Bs + (size_t)idx * 8, Bt + (size_t)(bn0 + row) * K + k0 + g * 8);
    }
    __syncthreads();
#pragma unroll
    for (int s = 0; s < 2; ++s) {  // two k-steps of 32
      bf16x8 af[TM], bfr[4];
#pragma unroll
      for (int ti = 0; ti < TM; ++ti) {
        int row = mbase + ti * 16 + c;
        af[ti] = *(const bf16x8*)(As + row * 64 + ((s * 4 + quad) ^ (row & 7)) * 8);
      }
#pragma unroll
      for (int tj = 0; tj < 4; ++tj) {
        int row = nbase + tj * 16 + c;
        bfr[tj] = *(const bf16x8*)(Bs + row * 64 + ((s * 4 + quad) ^ (row & 7)) * 8);
      }
#pragma unroll
      for (int ti = 0; ti < TM; ++ti)
#pragma unroll
        for (int tj = 0; tj < 4; ++tj)
          acc[ti][tj] = MFMA16(af[ti], bfr[tj], acc[ti][tj]);
    }
  }

  if constexpr (EPI == 2) {
    float* o = (float*)outp;
#pragma unroll
    for (int ti = 0; ti < TM; ++ti)
#pragma unroll
      for (int r = 0; r < 4; ++r) {
        int gm = bm0 + mbase + ti * 16 + quad * 4 + r;
        const float* rrow = resid + (size_t)gm * N;
        float* orow = o + (size_t)gm * N;
#pragma unroll
        for (int tj = 0; tj < 4; ++tj) {
          int gn = bn0 + nbase + tj * 16 + c;
          orow[gn] = acc[ti][tj][r] + b0[gn] + rrow[gn];
        }
      }
  } else if constexpr (EPI == 4) {
    bf16* act = (bf16*)outp;
#pragma unroll
    for (int ti = 0; ti < TM; ++ti)
#pragma unroll
      for (int r = 0; r < 4; ++r) {
        int gm = bm0 + mbase + ti * 16 + quad * 4 + r;
        bf16* arow = act + (size_t)gm * INTER_;
#pragma unroll
        for (int tj = 0; tj < 4; ++tj) {
          int gn = bn0 + nbase + tj * 16 + c;
          int g = gn >> 4, t = gn & 7, hi = (gn >> 3) & 1;
          float val = acc[ti][tj][r] + b0[g * 8 + t + (hi << 12)];
          float part = __shfl_xor(val, 8);  // partner col ^8 (h1 for h0 lanes)
          if (!hi) {
            float sg = part / (1.0f + __expf(-part));
            arow[g * 8 + t] = (bf16)(val * sg);
          }
        }
      }
  } else {  // EPI 0: fused QKV; mtx select is block-uniform (128 | 1024 tiles)
    bf16* o = (bf16*)outp;
    const int mtx = bn0 >> 10;  // 0=q 1=k 2=v
    const float* bp = (mtx == 0) ? b0 : (mtx == 1) ? b1p : b2p;
#pragma unroll
    for (int ti = 0; ti < TM; ++ti)
#pragma unroll
      for (int r = 0; r < 4; ++r) {
        int gm = bm0 + mbase + ti * 16 + quad * 4 + r;
        int s = gm & (S_ - 1);
        int bb = gm >> 11;
#pragma unroll
        for (int tj = 0; tj < 4; ++tj) {
          int gn = bn0 + nbase + tj * 16 + c;
          int ci = gn & 1023, hd = gn & 63;
          float val = acc[ti][tj][r] + bp[ci];
          if (mtx < 2) {
            int pj = (tj & 2) ? tj - 2 : tj + 2;
            int ci2 = (tj & 2) ? ci - 32 : ci + 32;
            float part = acc[ti][pj][r] + bp[ci2];
            if (!(tj & 2)) part = -part;
            float fr = rope[s * HD_ + hd];
            float sn, cs;
            __sincosf(fr, &sn, &cs);
            val = val * cs + part * sn;
            if (mtx == 0) val *= 0.1803368867f;  // (1/8) * log2(e)
          }
          o[(size_t)mtx * (32 * S_ * HD_) +
            (((size_t)(bb * H_ + ((gn >> 6) & 15))) * S_ + s) * HD_ + hd] =
              (bf16)val;
        }
      }
  }
}

// ---------------------------------------------------------------------------
// Flash attention: q(pre-scaled by log2e/8),k bf16 [B*H][S][HD],
// vt bf16 [B*H][HD][S], mask fp32 [B][S], ctx bf16 [B][S][Dm].
// Block = 64 q rows x head, 256 threads (4 waves x 16 q rows), KV tile 128
// processed as two 64-KV halves. LDS = Ks 16K + Vs 16K + Ps 8K = 40KB
// -> 4 blocks/CU (grid 1024 = 4/CU). No tight VGPR bound (spill hazard).
// ---------------------------------------------------------------------------
__global__ __launch_bounds__(256, 4) void flash_attn(
    const bf16* __restrict__ q, const bf16* __restrict__ k,
    const bf16* __restrict__ vt, const float* __restrict__ mask,
    bf16* __restrict__ ctx) {
  __shared__ __align__(16) bf16 Ks[128 * 64];   // [kv][hd], swizzled
  __shared__ __align__(16) bf16 Vs[64 * 128];   // [hd][s],  swizzled
  __shared__ __align__(16) bf16 Ps[4][16 * 64]; // per-wave P half-tile

  const int tid = threadIdx.x;
  const int lane = tid & 63, wave = tid >> 6;
  const int c = lane & 15, quad = lane >> 4;
  const int bh = blockIdx.y, b = bh >> 4, h = bh & 15;
  const int q0 = blockIdx.x * 64;

  const bf16* qh = q + (size_t)bh * S_ * HD_;
  const bf16* kh = k + (size_t)bh * S_ * HD_;
  const bf16* vh = vt + (size_t)bh * HD_ * S_;
  const float* mrow = mask + (size_t)b * S_;

  int qrow = q0 + wave * 16 + c;
  bf16x8 qa0 = *(const bf16x8*)(qh + (size_t)qrow * HD_ + quad * 8);
  bf16x8 qa1 = *(const bf16x8*)(qh + (size_t)qrow * HD_ + 32 + quad * 8);

  const f32x4 z4 = {0.f, 0.f, 0.f, 0.f};
  f32x4 o[4] = {z4, z4, z4, z4};
  float l_i[4] = {0.f, 0.f, 0.f, 0.f};
  bf16* pw = Ps[wave];

  for (int k0 = 0; k0 < S_; k0 += 128) {
    __syncthreads();
#pragma unroll
    for (int it = 0; it < 4; ++it) {  // Ks: 1024 chunks (row=128B=8 chunks)
      int idx = tid + it * 256;
      int row = idx >> 3, chg = (idx & 7) ^ (row & 7);
      cp16(Ks + (size_t)idx * 8, kh + (size_t)(k0 + row) * HD_ + chg * 8);
    }
#pragma unroll
    for (int it = 0; it < 4; ++it) {  // Vs: 1024 chunks (row=256B=16 chunks)
      int idx = tid + it * 256;
      int row = idx >> 4, chg = (idx & 15) ^ (row & 15);
      cp16(Vs + (size_t)idx * 8, vh + (size_t)row * S_ + k0 + chg * 8);
    }
    __syncthreads();

#pragma unroll
    for (int hh = 0; hh < 2; ++hh) {  // two 64-KV halves
      // S = Q K^T : 16 q rows x 64 kv cols per wave
      f32x4 sv[4];
      float mv2[4];
#pragma unroll
      for (int tj = 0; tj < 4; ++tj) {
        int krow = hh * 64 + tj * 16 + c;
        const bf16* kr = Ks + krow * 64;
        bf16x8 kb0 = *(const bf16x8*)(kr + (quad ^ (krow & 7)) * 8);
        bf16x8 kb1 = *(const bf16x8*)(kr + ((4 + quad) ^ (krow & 7)) * 8);
        sv[tj] = MFMA16(qa0, kb0, z4);
        sv[tj] = MFMA16(qa1, kb1, sv[tj]);
        mv2[tj] = mrow[k0 + krow] * 1.4426950408889634f;
      }

      // p = 2^(s + m*log2e); masked entries contribute to l but p := 0
#pragma unroll
      for (int tj = 0; tj < 4; ++tj) {
        bool msk = mv2[tj] < -1.4426950e-5f;
#pragma unroll
        for (int r = 0; r < 4; ++r) {
          float e = EXP2F(sv[tj][r] + mv2[tj]);
          l_i[r] += e;
          float p = msk ? 0.f : e;
          int prow = quad * 4 + r;
          int pos = (tj * 2 + (c >> 3)) ^ (prow & 7);
          pw[prow * 64 + pos * 8 + (c & 7)] = (bf16)p;
        }
      }
      asm volatile("s_waitcnt lgkmcnt(0)" ::: "memory");
      bf16x8 pa0 = *(const bf16x8*)(pw + c * 64 + (quad ^ (c & 7)) * 8);
      bf16x8 pa1 = *(const bf16x8*)(pw + c * 64 + ((quad + 4) ^ (c & 7)) * 8);

      // O += P V  (kv range hh*64 .. hh*64+63)
#pragma unroll
      for (int tn = 0; tn < 4; ++tn) {
        int vrow = tn * 16 + c;
        const bf16* vr = Vs + vrow * 128;
        bf16x8 vb0 =
            *(const bf16x8*)(vr + (((hh * 2 + 0) * 4 + quad) ^ (vrow & 15)) * 8);
        bf16x8 vb1 =
            *(const bf16x8*)(vr + (((hh * 2 + 1) * 4 + quad) ^ (vrow & 15)) * 8);
        o[tn] = MFMA16(pa0, vb0, o[tn]);
        o[tn] = MFMA16(pa1, vb1, o[tn]);
      }
    }
  }

  // deferred 16-lane l reduction + epilogue
#pragma unroll
  for (int r = 0; r < 4; ++r) {
    float l = l_i[r];
#pragma unroll
    for (int off = 1; off < 16; off <<= 1) l += __shfl_xor(l, off);
    float inv = 1.0f / l;
    int qout = q0 + wave * 16 + quad * 4 + r;
    bf16* crow = ctx + ((size_t)(b * S_ + qout)) * DM_ + h * HD_;
#pragma unroll
    for (int tn = 0; tn < 4; ++tn) crow[tn * 16 + c] = (bf16)(o[tn][r] * inv);
  }
}

// ---------------------------------------------------------------------------
// Launch
// ---------------------------------------------------------------------------
extern "C" void kernel_launch(void* const* d_in, const int* in_sizes, int n_in,
                              void* d_out, int out_size, void* d_ws,
                              size_t ws_size, hipStream_t stream) {
  const float* hs   = (const float*)d_in[0];
  const float* mask = (const float*)d_in[1];
  const float* rope = (const float*)d_in[2];
  const float* Wq = (const float*)d_in[3];  const float* bq = (const float*)d_in[4];
  const float* Wk = (const float*)d_in[5];  const float* bk = (const float*)d_in[6];
  const float* Wv = (const float*)d_in[7];  const float* bv = (const float*)d_in[8];
  const float* Wo = (const float*)d_in[9];  const float* bo = (const float*)d_in[10];
  const float* g1 = (const float*)d_in[11]; const float* be1 = (const float*)d_in[12];
  const float* g2 = (const float*)d_in[13]; const float* be2 = (const float*)d_in[14];
  const float* W1 = (const float*)d_in[15]; const float* b1 = (const float*)d_in[16];
  const float* W2 = (const float*)d_in[17]; const float* b2 = (const float*)d_in[18];
  float* out = (float*)d_out;
  char* ws = (char*)d_ws;
  const size_t MB = 1ull << 20;

  // workspace layout (peak 128 MiB)
  bf16* Wqkvt = (bf16*)(ws + 0 * MB);    // [3072][1024]  (6 MB)
  bf16* Wot = (bf16*)(ws + 6 * MB);      // [1024][1024]  (2 MB)
  bf16* W1t = (bf16*)(ws + 8 * MB);      // [8192][1024] interleaved (16 MB)
  bf16* W2t = (bf16*)(ws + 24 * MB);     // [1024][4096]  (8 MB)
  bf16* xln = (bf16*)(ws + 32 * MB);     // [4096][1024]  (8 MB)
  float* hid = (float*)(ws + 40 * MB);   // [4096][1024] fp32 (16 MB)
  bf16* qkv = (bf16*)(ws + 56 * MB);     // 3 x [32][2048][64]  (24 MB)
  bf16* vtr = (bf16*)(ws + 80 * MB);     // [32][64][2048]  (8 MB)
  bf16* ctx = (bf16*)(ws + 88 * MB);     // [4096][1024]  (8 MB)
  bf16* act = (bf16*)(ws + 96 * MB);     // [4096][4096]  (32 MB)

  dim3 blk(256);
  dim3 tb(32, 8);

  // weight conversion + transpose
  transpose4_f32_bf16<<<dim3(32, 32, 4), tb, 0, stream>>>(
      Wq, Wk, Wv, Wo, Wqkvt, Wqkvt + (1 << 20), Wqkvt + (2 << 20), Wot);
  transpose_w1<<<dim3(256, 32), tb, 0, stream>>>(W1, W1t);
  transpose_f32_bf16<<<dim3(32, 128), tb, 0, stream>>>(W2, W2t, 4096, 1024);

  // LN1
  ln_bf16<<<4096, blk, 0, stream>>>(hs, g1, be1, xln);

  // fused QKV projection (RoPE q/k, scale into q, heads layout)
  gemm_bt<0, 128><<<dim3(24, 32), blk, 0, stream>>>(
      xln, Wqkvt, bq, bk, bv, rope, nullptr, qkv, 3072, 1024);

  // V -> V^T per head
  transpose_bf16<<<dim3(2, 64, 32), tb, 0, stream>>>(
      qkv + (size_t)2 * 32 * S_ * HD_, vtr, 2048, 64);

  // flash attention (64 q rows per block, 256 threads, 4 blocks/CU)
  flash_attn<<<dim3(32, 32), dim3(256), 0, stream>>>(
      qkv, qkv + (size_t)32 * S_ * HD_, vtr, mask, ctx);

  // Wo projection + residual -> hidden (fp32)
  gemm_bt<2, 64><<<dim3(16, 32), blk, 0, stream>>>(
      ctx, Wot, bo, nullptr, nullptr, nullptr, hs, hid, 1024, 1024);

  // LN2
  ln_bf16<<<4096, blk, 0, stream>>>(hid, g2, be2, xln);

  // W1 GEMM + fused swiglu -> act
  gemm_bt<4, 128><<<dim3(64, 32), blk, 0, stream>>>(
      xln, W1t, b1, nullptr, nullptr, nullptr, nullptr, act, 8192, 1024);

  // W2 GEMM + residual -> out (fp32)
  gemm_bt<2, 64><<<dim3(16, 32), blk, 0, stream>>>(
      act, W2t, b2, nullptr, nullptr, nullptr, hid, out, 1024, 4096);

  (void)in_sizes; (void)n_in; (void)out_size; (void)ws_size;
}